// Round 1
// baseline (184.087 us; speedup 1.0000x reference)
//
#include <hip/hip_runtime.h>

#define C 4096
#define NROWS 16384

// ---------------------------------------------------------------------------
// Kernel 1: column sums of x [NROWS, C] -> gsum [C] (fp32 atomics)
// grid = (C/1024, 256), block = 256. Each thread owns 4 consecutive columns
// (one float4) over a 64-row slice; coalesced 4 KB/row per block.
// ---------------------------------------------------------------------------
__global__ void colsum_kernel(const float* __restrict__ x, float* __restrict__ gsum) {
    const int c4 = blockIdx.x * blockDim.x + threadIdx.x;   // float4 column, 0..1023
    const int rows_per = NROWS / gridDim.y;
    const int r0 = blockIdx.y * rows_per;
    const float4* xv = (const float4*)x;
    float4 acc = make_float4(0.f, 0.f, 0.f, 0.f);
    for (int r = r0; r < r0 + rows_per; ++r) {
        float4 v = xv[(size_t)r * (C / 4) + c4];
        acc.x += v.x; acc.y += v.y; acc.z += v.z; acc.w += v.w;
    }
    float* g = gsum + c4 * 4;
    atomicAdd(g + 0, acc.x);
    atomicAdd(g + 1, acc.y);
    atomicAdd(g + 2, acc.z);
    atomicAdd(g + 3, acc.w);
}

// ---------------------------------------------------------------------------
// Kernel 2: y[i] = sigmoid( sf * ( dot(W[i,:], gsum)/NROWS + b[i] ) )
// One 256-thread block per row of W; float4 loads, strided for coalescing.
// Writes x_scale into the tail of d_out.
// ---------------------------------------------------------------------------
__global__ void matvec_kernel(const float* __restrict__ W,
                              const float* __restrict__ b,
                              const float* __restrict__ gsum,
                              const int* __restrict__ sf,
                              float* __restrict__ scale_out) {
    const int row = blockIdx.x;
    const int t = threadIdx.x;  // 256
    const float4* wv = (const float4*)(W + (size_t)row * C);
    const float4* gv = (const float4*)gsum;
    float acc = 0.f;
#pragma unroll
    for (int k = 0; k < 4; ++k) {
        const int j4 = t + k * 256;         // 0..1023, coalesced per k
        const float4 w = wv[j4];
        const float4 g = gv[j4];
        acc += w.x * g.x + w.y * g.y + w.z * g.z + w.w * g.w;
    }
    // wave (64-lane) reduction
#pragma unroll
    for (int off = 32; off > 0; off >>= 1) acc += __shfl_down(acc, off);
    __shared__ float red[4];
    if ((t & 63) == 0) red[t >> 6] = acc;
    __syncthreads();
    if (t == 0) {
        const float y = (red[0] + red[1] + red[2] + red[3]) * (1.0f / NROWS) + b[row];
        const float z = y * (float)sf[0];
        const float s = 1.0f / (1.0f + __expf(-z));
        scale_out[row] = s;
    }
}

// ---------------------------------------------------------------------------
// Kernel 3: out[n][c] = x[n][c] * s[c]   (float4 grid-stride)
// s is 16 KiB -> L2-resident; C/4 = 1024 is pow2 so (i & 1023) indexes s.
// ---------------------------------------------------------------------------
__global__ void scale_kernel(const float* __restrict__ x,
                             const float* __restrict__ s,
                             float* __restrict__ out) {
    const float4* xv = (const float4*)x;
    const float4* sv = (const float4*)s;
    float4* ov = (float4*)out;
    const size_t total = (size_t)NROWS * C / 4;
    for (size_t i = (size_t)blockIdx.x * blockDim.x + threadIdx.x; i < total;
         i += (size_t)gridDim.x * blockDim.x) {
        float4 v = xv[i];
        const float4 sc = sv[i & 1023];
        v.x *= sc.x; v.y *= sc.y; v.z *= sc.z; v.w *= sc.w;
        ov[i] = v;
    }
}

extern "C" void kernel_launch(void* const* d_in, const int* in_sizes, int n_in,
                              void* d_out, int out_size, void* d_ws, size_t ws_size,
                              hipStream_t stream) {
    const float* x = (const float*)d_in[0];   // [NROWS, C] fp32
    const float* W = (const float*)d_in[1];   // [C, C] fp32
    const float* b = (const float*)d_in[2];   // [C] fp32
    const int* sf  = (const int*)d_in[3];     // scalar int

    float* out = (float*)d_out;               // [NROWS*C] x_out ++ [C] x_scale
    float* scale_tail = out + (size_t)NROWS * C;
    float* gsum = (float*)d_ws;               // [C] column sums

    hipMemsetAsync(gsum, 0, C * sizeof(float), stream);

    colsum_kernel<<<dim3(C / 1024, 256), 256, 0, stream>>>(x, gsum);
    matvec_kernel<<<C, 256, 0, stream>>>(W, b, gsum, sf, scale_tail);
    scale_kernel<<<2048, 256, 0, stream>>>(x, scale_tail, out);
}

// Round 2
// 159.024 us; speedup vs baseline: 1.1576x; 1.1576x over previous
//
#include <hip/hip_runtime.h>

#define C 4096
#define NROWS 16384
#define PARTS 256   // row-slices for colsum partials

typedef float f32x4 __attribute__((ext_vector_type(4)));

// ---------------------------------------------------------------------------
// Kernel 1: per-slice column partial sums. grid=(C/1024, PARTS), block=256.
// Each block sums a 64-row slice for its 1024-float column group and writes
// its partial row to ws (no atomics). x stays resident in L3 (regular loads).
// ---------------------------------------------------------------------------
__global__ void colsum_partial(const float* __restrict__ x, float* __restrict__ part) {
    const int c4 = blockIdx.x * blockDim.x + threadIdx.x;   // float4 column, 0..1023
    const int rows_per = NROWS / PARTS;                      // 64
    const int r0 = blockIdx.y * rows_per;
    const f32x4* xv = (const f32x4*)x;
    f32x4 acc = {0.f, 0.f, 0.f, 0.f};
#pragma unroll 4
    for (int r = 0; r < rows_per; ++r) {
        acc += xv[(size_t)(r0 + r) * (C / 4) + c4];
    }
    ((f32x4*)part)[(size_t)blockIdx.y * (C / 4) + c4] = acc;
}

// ---------------------------------------------------------------------------
// Kernel 2: fold PARTS partial rows -> gsum [C]. grid=16, block=256.
// Reads 4 MiB (L2-hot), writes 16 KiB.
// ---------------------------------------------------------------------------
__global__ void colsum_reduce(const float* __restrict__ part, float* __restrict__ gsum) {
    const int c = blockIdx.x * blockDim.x + threadIdx.x;     // 0..4095
    float s = 0.f;
#pragma unroll 8
    for (int r = 0; r < PARTS; ++r) s += part[(size_t)r * C + c];
    gsum[c] = s;
}

// ---------------------------------------------------------------------------
// Kernel 3: y[i] = sigmoid( sf * ( dot(W[i,:], gsum)/NROWS + b[i] ) )
// One 256-thread block per row. W via NONTEMPORAL loads so the 64 MiB W
// stream does not evict x from the Infinity Cache.
// ---------------------------------------------------------------------------
__global__ void matvec_kernel(const float* __restrict__ W,
                              const float* __restrict__ b,
                              const float* __restrict__ gsum,
                              const int* __restrict__ sf,
                              float* __restrict__ scale_out) {
    const int row = blockIdx.x;
    const int t = threadIdx.x;  // 256
    const f32x4* wv = (const f32x4*)(W + (size_t)row * C);
    const f32x4* gv = (const f32x4*)gsum;
    float acc = 0.f;
#pragma unroll
    for (int k = 0; k < 4; ++k) {
        const int j4 = t + k * 256;          // coalesced per k
        const f32x4 w = __builtin_nontemporal_load(wv + j4);
        const f32x4 g = gv[j4];
        acc += w.x * g.x + w.y * g.y + w.z * g.z + w.w * g.w;
    }
#pragma unroll
    for (int off = 32; off > 0; off >>= 1) acc += __shfl_down(acc, off);
    __shared__ float red[4];
    if ((t & 63) == 0) red[t >> 6] = acc;
    __syncthreads();
    if (t == 0) {
        const float y = (red[0] + red[1] + red[2] + red[3]) * (1.0f / NROWS) + b[row];
        const float z = y * (float)sf[0];
        const float s = 1.0f / (1.0f + __expf(-z));
        scale_out[row] = s;
    }
}

// ---------------------------------------------------------------------------
// Kernel 4: out[n][c] = x[n][c] * s[c]. REVERSE-order grid-stride (MRU-first
// re-scan of x after colsum -> L3 hits instead of LRU-cascade misses) and
// NONTEMPORAL stores (write stream does not allocate / evict x).
// ---------------------------------------------------------------------------
__global__ void scale_kernel(const float* __restrict__ x,
                             const float* __restrict__ s,
                             float* __restrict__ out) {
    const f32x4* xv = (const f32x4*)x;
    const f32x4* sv = (const f32x4*)s;
    f32x4* ov = (f32x4*)out;
    const int tid = threadIdx.x;
    const long K = (long)NROWS * C / 4 / 256;   // 65536 chunks of 256 float4
    for (long k = K - 1 - blockIdx.x; k >= 0; k -= gridDim.x) {
        const size_t i = (size_t)k * 256 + tid;
        f32x4 v = xv[i];
        const f32x4 sc = sv[i & 1023];
        v *= sc;
        __builtin_nontemporal_store(v, ov + i);
    }
}

extern "C" void kernel_launch(void* const* d_in, const int* in_sizes, int n_in,
                              void* d_out, int out_size, void* d_ws, size_t ws_size,
                              hipStream_t stream) {
    const float* x = (const float*)d_in[0];   // [NROWS, C] fp32
    const float* W = (const float*)d_in[1];   // [C, C] fp32
    const float* b = (const float*)d_in[2];   // [C] fp32
    const int* sf  = (const int*)d_in[3];     // scalar int

    float* out = (float*)d_out;               // [NROWS*C] x_out ++ [C] x_scale
    float* scale_tail = out + (size_t)NROWS * C;

    float* part = (float*)d_ws;               // [PARTS][C] partial sums (4 MiB)
    float* gsum = part + (size_t)PARTS * C;   // [C]

    colsum_partial<<<dim3(C / 1024, PARTS), 256, 0, stream>>>(x, part);
    colsum_reduce<<<C / 256, 256, 0, stream>>>(part, gsum);
    matvec_kernel<<<C, 256, 0, stream>>>(W, b, gsum, sf, scale_tail);
    scale_kernel<<<2048, 256, 0, stream>>>(x, scale_tail, out);
}